// Round 7
// baseline (5691.496 us; speedup 1.0000x reference)
//
#include <hip/hip_runtime.h>

#define TT 512
#define BB 64
#define HH 1024
#define EE 512
#define VV 50000
#define BBHH (BB*HH)
#define BPL 128
#define NBLK 256

typedef __attribute__((ext_vector_type(8))) short bf16x8;
typedef __attribute__((ext_vector_type(4))) float f32x4;
typedef unsigned short us;

#define MFMA(a,b,c) __builtin_amdgcn_mfma_f32_16x16x32_bf16((a),(b),(c),0,0,0)
#define LDG(p) __hip_atomic_load((p), __ATOMIC_RELAXED, __HIP_MEMORY_SCOPE_AGENT)
#define ZIDX(ks,m,ntg,ln) (((((ks)*2+(m))*4+(ntg))*64+(ln))*4)

__device__ inline us f2b(float f){
  unsigned u; __builtin_memcpy(&u, &f, 4);
  return (us)((u + 0x7FFFu + ((u >> 16) & 1u)) >> 16);
}
__device__ inline float sigmoidf_(float x){ return 1.0f / (1.0f + __expf(-x)); }
__device__ inline float tanhf_(float x){ float e = __expf(2.0f * x); return 1.0f - 2.0f / (e + 1.0f); }

__device__ inline bf16x8 pack8(float4 a, float4 b){
  bf16x8 r;
  r[0]=(short)f2b(a.x); r[1]=(short)f2b(a.y); r[2]=(short)f2b(a.z); r[3]=(short)f2b(a.w);
  r[4]=(short)f2b(b.x); r[5]=(short)f2b(b.y); r[6]=(short)f2b(b.z); r[7]=(short)f2b(b.w);
  return r;
}

// ---------------- cast fp32 -> bf16 ----------------
__global__ void cast_f2b(const float* __restrict__ src, us* __restrict__ dst, long n){
  long i = ((long)blockIdx.x * blockDim.x + threadIdx.x) * 4;
  long stride = (long)gridDim.x * blockDim.x * 4;
  for (; i + 3 < n; i += stride){
    float4 v = *reinterpret_cast<const float4*>(src + i);
    ushort4 r; r.x=f2b(v.x); r.y=f2b(v.y); r.z=f2b(v.z); r.w=f2b(v.w);
    *reinterpret_cast<ushort4*>(dst + i) = r;
  }
}

// ---------------- init: h0 fp32 [2,B,H] -> compact [j>>3][b][j&7] bf16 ----------------
__global__ void init_h(const float* __restrict__ h0,
                       us* __restrict__ h0ic, us* __restrict__ h1ic){
  int i = blockIdx.x * blockDim.x + threadIdx.x;   // b*HH + j
  int b = i >> 10, j = i & (HH - 1);
  int d = (((j >> 3) * BB) + b) * 8 + (j & 7);
  h0ic[d] = f2b(h0[i]);
  h1ic[d] = f2b(h0[BBHH + i]);
}

// ---------------- sync primitives ----------------
__device__ __forceinline__ void poll_flags(const unsigned* f, unsigned e, int lane){
  for(;;){
    unsigned a = LDG(f + lane);
    unsigned b = LDG(f + 64 + lane);
    if (__all((int)(a >= e && b >= e))) break;
    __builtin_amdgcn_s_sleep(1);
  }
}
__device__ __forceinline__ void wave_gate(unsigned* go, unsigned gval,
                                          const unsigned* f, unsigned e, int lane, int wid){
  if (wid == 0){
    poll_flags(f, e, lane);
    __hip_atomic_store(go, gval, __ATOMIC_RELAXED, __HIP_MEMORY_SCOPE_WORKGROUP);
  } else {
    while (__hip_atomic_load(go, __ATOMIC_RELAXED, __HIP_MEMORY_SCOPE_WORKGROUP) < gval)
      __builtin_amdgcn_s_sleep(1);
  }
}
__device__ __forceinline__ void lds_spin(unsigned* c, unsigned tgt){
  while (__hip_atomic_load(c, __ATOMIC_RELAXED, __HIP_MEMORY_SCOPE_WORKGROUP) < tgt)
    __builtin_amdgcn_s_sleep(1);
}

// ---------------- layer 0 (blocks 0..127) ----------------
__device__ void run_l0(int bid_l, const int* __restrict__ inputs, const float* __restrict__ c0,
    const us* __restrict__ emb_bf, const float* __restrict__ Wih0, const float* __restrict__ Whh0,
    const us* __restrict__ h0ic, us* __restrict__ hist0,
    float* __restrict__ hn, float* __restrict__ cn,
    unsigned* __restrict__ flags0,
    float* zone, unsigned* ctrA, unsigned* ctrR, unsigned* ctrP, unsigned* go0)
{
  const int tid = threadIdx.x, lane = tid & 63, wid = tid >> 6;
  const int l16 = lane & 15, hi = lane >> 4, kq = hi << 3;
  const int ks = wid & 3, bh = wid >> 2;
  const int j0 = bid_l * 8;

  bf16x8 wx[2][4], wh[2][8];
  #pragma unroll
  for (int m = 0; m < 2; ++m){
    const int g = l16 & 3, u = 2 * (l16 >> 2) + m;
    const float* rx = Wih0 + (size_t)(g * HH + j0 + u) * EE;
    const float* rh = Whh0 + (size_t)(g * HH + j0 + u) * HH;
    #pragma unroll
    for (int kk = 0; kk < 4; ++kk){
      int k0 = ks * 128 + kk * 32 + kq;
      wx[m][kk] = pack8(*(const float4*)(rx + k0), *(const float4*)(rx + k0 + 4));
    }
    #pragma unroll
    for (int kk = 0; kk < 8; ++kk){
      int k0 = ks * 256 + kk * 32 + kq;
      wh[m][kk] = pack8(*(const float4*)(rh + k0), *(const float4*)(rh + k0 + 4));
    }
  }

  const int bown  = wid * 8 + (lane >> 2);
  const int u0    = 2 * (lane & 3);
  const int ntg_r = bown >> 4;
  const int lam   = (lane & 3) * 16 + (bown & 15);
  float cs0 = 0.f, cs1 = 0.f;
  if (lane < 32){
    cs0 = c0[(size_t)bown * HH + j0 + u0];
    cs1 = c0[(size_t)bown * HH + j0 + u0 + 1];
  }

  for (int t = 0; t < TT; ++t){
    f32x4 acc[2][2];
    acc[0][0]=acc[0][1]=acc[1][0]=acc[1][1]=(f32x4){0.f,0.f,0.f,0.f};

    // A: dependency-free x-part (emb)
    {
      const us* xr0 = emb_bf + (size_t)inputs[t*BB + bh*32 + l16] * EE;
      const us* xr1 = emb_bf + (size_t)inputs[t*BB + bh*32 + 16 + l16] * EE;
      #pragma unroll
      for (int kk = 0; kk < 4; ++kk){
        const int kb = ks * 128 + kk * 32 + kq;
        bf16x8 b0 = *(const bf16x8*)(xr0 + kb);
        bf16x8 b1 = *(const bf16x8*)(xr1 + kb);
        acc[0][0] = MFMA(wx[0][kk], b0, acc[0][0]);
        acc[1][0] = MFMA(wx[1][kk], b0, acc[1][0]);
        acc[0][1] = MFMA(wx[0][kk], b1, acc[0][1]);
        acc[1][1] = MFMA(wx[1][kk], b1, acc[1][1]);
      }
    }

    // B: drain previous publish (hidden under A), raise flag t
    if (t > 0){
      asm volatile("s_waitcnt vmcnt(0)" ::: "memory");
      if (lane == 0){
        unsigned old = atomicAdd(ctrP, 1u);
        if (old == 8u * (unsigned)t - 1u)
          __hip_atomic_store(flags0 + bid_l, (unsigned)t, __ATOMIC_RELAXED, __HIP_MEMORY_SCOPE_AGENT);
      }
    }

    // C: wait all L0 flags >= t
    if (t > 0) wave_gate(go0, (unsigned)t, flags0, (unsigned)t, lane, wid);

    // D: recurrent h-part
    {
      const us* hs = (t == 0) ? h0ic : hist0 + (size_t)(t - 1) * BBHH;
      #pragma unroll
      for (int kk = 0; kk < 8; ++kk){
        const us* p = hs + (size_t)(ks * 32 + kk * 4 + hi) * 512;
        bf16x8 b0 = *(const bf16x8*)(p + (bh*32 + l16) * 8);
        bf16x8 b1 = *(const bf16x8*)(p + (bh*32 + 16 + l16) * 8);
        acc[0][0] = MFMA(wh[0][kk], b0, acc[0][0]);
        acc[1][0] = MFMA(wh[1][kk], b0, acc[1][0]);
        acc[0][1] = MFMA(wh[0][kk], b1, acc[0][1]);
        acc[1][1] = MFMA(wh[1][kk], b1, acc[1][1]);
      }
    }

    // E: zone reuse gate
    if (t > 0) lds_spin(ctrR, 8u * (unsigned)t);

    // F: zone write + writes-done counter
    #pragma unroll
    for (int m = 0; m < 2; ++m)
      #pragma unroll
      for (int ntl = 0; ntl < 2; ++ntl)
        *(f32x4*)&zone[ZIDX(ks, m, bh*2 + ntl, lane)] = acc[m][ntl];
    asm volatile("s_waitcnt lgkmcnt(0)" ::: "memory");
    if (lane == 0) atomicAdd(ctrA, 1u);
    lds_spin(ctrA, 8u * (unsigned)(t + 1));

    // G/H: read sums, cell update, publish (issue only)
    if (lane < 32){
      f32x4 s0 = (f32x4){0.f,0.f,0.f,0.f}, s1 = (f32x4){0.f,0.f,0.f,0.f};
      #pragma unroll
      for (int kr = 0; kr < 4; ++kr){
        s0 += *(f32x4*)&zone[ZIDX(kr, 0, ntg_r, lam)];
        s1 += *(f32x4*)&zone[ZIDX(kr, 1, ntg_r, lam)];
      }
      float gi = sigmoidf_(s0[0]), gf = sigmoidf_(s0[1]);
      float gg = tanhf_(s0[2]),    go = sigmoidf_(s0[3]);
      cs0 = gf * cs0 + gi * gg;
      float hv0 = go * tanhf_(cs0);
      gi = sigmoidf_(s1[0]); gf = sigmoidf_(s1[1]);
      gg = tanhf_(s1[2]);    go = sigmoidf_(s1[3]);
      cs1 = gf * cs1 + gi * gg;
      float hv1 = go * tanhf_(cs1);

      unsigned w = (unsigned)f2b(hv0) | ((unsigned)f2b(hv1) << 16);
      __hip_atomic_store((unsigned*)(hist0 + (size_t)t * BBHH + ((size_t)(bid_l*64 + bown))*8 + u0),
                         w, __ATOMIC_RELAXED, __HIP_MEMORY_SCOPE_AGENT);
      if (t == TT - 1){
        size_t o = (size_t)bown * HH + j0 + u0;
        *reinterpret_cast<float2*>(hn + o) = make_float2(hv0, hv1);
        *reinterpret_cast<float2*>(cn + o) = make_float2(cs0, cs1);
      }
    }
    asm volatile("s_waitcnt lgkmcnt(0)" ::: "memory");
    if (lane == 0) atomicAdd(ctrR, 1u);
  }

  // final drain + flag TT
  asm volatile("s_waitcnt vmcnt(0)" ::: "memory");
  if (lane == 0){
    unsigned old = atomicAdd(ctrP, 1u);
    if (old == 8u * (unsigned)TT - 1u)
      __hip_atomic_store(flags0 + bid_l, (unsigned)TT, __ATOMIC_RELAXED, __HIP_MEMORY_SCOPE_AGENT);
  }
}

// ---------------- layer 1 (blocks 128..255) ----------------
__device__ void run_l1(int bid_l, const float* __restrict__ c0,
    const float* __restrict__ Wih1, const float* __restrict__ Whh1,
    const us* __restrict__ h1ic, const us* __restrict__ hist0, us* __restrict__ hist1,
    const float* __restrict__ decW, const float* __restrict__ decb,
    float* __restrict__ dec_out, float* __restrict__ hn, float* __restrict__ cn,
    unsigned* __restrict__ flags0, unsigned* __restrict__ flags1,
    float* zone, unsigned* ctrA, unsigned* ctrR, unsigned* ctrP,
    unsigned* go1, unsigned* go2)
{
  const int tid = threadIdx.x, lane = tid & 63, wid = tid >> 6;
  const int l16 = lane & 15, hi = lane >> 4, kq = hi << 3;
  const int ks = wid & 3, bh = wid >> 2;
  const int j0 = bid_l * 8;

  bf16x8 wx[2][8], wh[2][8];
  #pragma unroll
  for (int m = 0; m < 2; ++m){
    const int g = l16 & 3, u = 2 * (l16 >> 2) + m;
    const float* rx = Wih1 + (size_t)(g * HH + j0 + u) * HH;
    const float* rh = Whh1 + (size_t)(g * HH + j0 + u) * HH;
    #pragma unroll
    for (int kk = 0; kk < 8; ++kk){
      int k0 = ks * 256 + kk * 32 + kq;
      wx[m][kk] = pack8(*(const float4*)(rx + k0), *(const float4*)(rx + k0 + 4));
      wh[m][kk] = pack8(*(const float4*)(rh + k0), *(const float4*)(rh + k0 + 4));
    }
  }

  const int bown  = wid * 8 + (lane >> 2);
  const int u0    = 2 * (lane & 3);
  const int ntg_r = bown >> 4;
  const int lam   = (lane & 3) * 16 + (bown & 15);
  float cs0 = 0.f, cs1 = 0.f, pooldec = 0.f, dw0 = 0.f, dw1 = 0.f;
  if (lane < 32){
    cs0 = c0[(size_t)BBHH + (size_t)bown * HH + j0 + u0];
    cs1 = c0[(size_t)BBHH + (size_t)bown * HH + j0 + u0 + 1];
    dw0 = decW[j0 + u0]; dw1 = decW[j0 + u0 + 1];
  }

  for (int t = 0; t < TT; ++t){
    f32x4 acc[2][2];
    acc[0][0]=acc[0][1]=acc[1][0]=acc[1][1]=(f32x4){0.f,0.f,0.f,0.f};

    // B: drain previous publish, raise flag1 t (must precede own-flag wait)
    if (t > 0){
      asm volatile("s_waitcnt vmcnt(0)" ::: "memory");
      if (lane == 0){
        unsigned old = atomicAdd(ctrP, 1u);
        if (old == 8u * (unsigned)t - 1u)
          __hip_atomic_store(flags1 + bid_l, (unsigned)t, __ATOMIC_RELAXED, __HIP_MEMORY_SCOPE_AGENT);
      }
    }

    // A: recurrent part (own layer, usually already satisfied)
    if (t > 0) wave_gate(go1, (unsigned)t, flags1, (unsigned)t, lane, wid);
    {
      const us* hs = (t == 0) ? h1ic : hist1 + (size_t)(t - 1) * BBHH;
      #pragma unroll
      for (int kk = 0; kk < 8; ++kk){
        const us* p = hs + (size_t)(ks * 32 + kk * 4 + hi) * 512;
        bf16x8 b0 = *(const bf16x8*)(p + (bh*32 + l16) * 8);
        bf16x8 b1 = *(const bf16x8*)(p + (bh*32 + 16 + l16) * 8);
        acc[0][0] = MFMA(wh[0][kk], b0, acc[0][0]);
        acc[1][0] = MFMA(wh[1][kk], b0, acc[1][0]);
        acc[0][1] = MFMA(wh[0][kk], b1, acc[0][1]);
        acc[1][1] = MFMA(wh[1][kk], b1, acc[1][1]);
      }
    }

    // C: wait h0[t] published (flags0 >= t+1)
    wave_gate(go2, (unsigned)(t + 1), flags0, (unsigned)(t + 1), lane, wid);

    // D: x-part from h0[t]
    {
      const us* xs = hist0 + (size_t)t * BBHH;
      #pragma unroll
      for (int kk = 0; kk < 8; ++kk){
        const us* p = xs + (size_t)(ks * 32 + kk * 4 + hi) * 512;
        bf16x8 b0 = *(const bf16x8*)(p + (bh*32 + l16) * 8);
        bf16x8 b1 = *(const bf16x8*)(p + (bh*32 + 16 + l16) * 8);
        acc[0][0] = MFMA(wx[0][kk], b0, acc[0][0]);
        acc[1][0] = MFMA(wx[1][kk], b0, acc[1][0]);
        acc[0][1] = MFMA(wx[0][kk], b1, acc[0][1]);
        acc[1][1] = MFMA(wx[1][kk], b1, acc[1][1]);
      }
    }

    // E: zone reuse gate
    if (t > 0) lds_spin(ctrR, 8u * (unsigned)t);

    // F: zone write
    #pragma unroll
    for (int m = 0; m < 2; ++m)
      #pragma unroll
      for (int ntl = 0; ntl < 2; ++ntl)
        *(f32x4*)&zone[ZIDX(ks, m, bh*2 + ntl, lane)] = acc[m][ntl];
    asm volatile("s_waitcnt lgkmcnt(0)" ::: "memory");
    if (lane == 0) atomicAdd(ctrA, 1u);
    lds_spin(ctrA, 8u * (unsigned)(t + 1));

    // G/H: read, cell, publish issue
    if (lane < 32){
      f32x4 s0 = (f32x4){0.f,0.f,0.f,0.f}, s1 = (f32x4){0.f,0.f,0.f,0.f};
      #pragma unroll
      for (int kr = 0; kr < 4; ++kr){
        s0 += *(f32x4*)&zone[ZIDX(kr, 0, ntg_r, lam)];
        s1 += *(f32x4*)&zone[ZIDX(kr, 1, ntg_r, lam)];
      }
      float gi = sigmoidf_(s0[0]), gf = sigmoidf_(s0[1]);
      float gg = tanhf_(s0[2]),    go = sigmoidf_(s0[3]);
      cs0 = gf * cs0 + gi * gg;
      float hv0 = go * tanhf_(cs0);
      gi = sigmoidf_(s1[0]); gf = sigmoidf_(s1[1]);
      gg = tanhf_(s1[2]);    go = sigmoidf_(s1[3]);
      cs1 = gf * cs1 + gi * gg;
      float hv1 = go * tanhf_(cs1);

      unsigned w = (unsigned)f2b(hv0) | ((unsigned)f2b(hv1) << 16);
      __hip_atomic_store((unsigned*)(hist1 + (size_t)t * BBHH + ((size_t)(bid_l*64 + bown))*8 + u0),
                         w, __ATOMIC_RELAXED, __HIP_MEMORY_SCOPE_AGENT);
      pooldec += hv0 * dw0 + hv1 * dw1;
      if (t == TT - 1){
        size_t o = (size_t)BBHH + (size_t)bown * HH + j0 + u0;
        *reinterpret_cast<float2*>(hn + o) = make_float2(hv0, hv1);
        *reinterpret_cast<float2*>(cn + o) = make_float2(cs0, cs1);
      }
    }
    asm volatile("s_waitcnt lgkmcnt(0)" ::: "memory");
    if (lane == 0) atomicAdd(ctrR, 1u);
  }

  asm volatile("s_waitcnt vmcnt(0)" ::: "memory");
  if (lane == 0){
    unsigned old = atomicAdd(ctrP, 1u);
    if (old == 8u * (unsigned)TT - 1u)
      __hip_atomic_store(flags1 + bid_l, (unsigned)TT, __ATOMIC_RELAXED, __HIP_MEMORY_SCOPE_AGENT);
  }

  // decode
  pooldec += __shfl_xor(pooldec, 1);
  pooldec += __shfl_xor(pooldec, 2);
  if (lane < 32 && (lane & 3) == 0){
    float contrib = pooldec * (1.0f / (float)TT);
    if (bid_l == 0) contrib += decb[0];
    atomicAdd(&dec_out[bown], contrib);
  }
}

__global__ __launch_bounds__(512, 2) void lstm_persist(
    const int* __restrict__ inputs, const float* __restrict__ c0,
    const us* __restrict__ emb_bf,
    const float* __restrict__ Wih0, const float* __restrict__ Whh0,
    const float* __restrict__ Wih1, const float* __restrict__ Whh1,
    const us* __restrict__ h0ic, const us* __restrict__ h1ic,
    us* __restrict__ hist0, us* __restrict__ hist1,
    const float* __restrict__ decW, const float* __restrict__ decb,
    float* __restrict__ dec_out, float* __restrict__ hn, float* __restrict__ cn,
    unsigned* __restrict__ flags)
{
  __shared__ float zone[4*2*4*64*4];            // 32 KB
  __shared__ unsigned ctrA, ctrR, ctrP, goA, goB;
  if (threadIdx.x == 0){ ctrA = 0; ctrR = 0; ctrP = 0; goA = 0; goB = 0; }
  __syncthreads();

  unsigned* flags0 = flags;
  unsigned* flags1 = flags + 128;
  int bid = blockIdx.x;
  if (bid < BPL){
    run_l0(bid, inputs, c0, emb_bf, Wih0, Whh0, h0ic, hist0, hn, cn,
           flags0, zone, &ctrA, &ctrR, &ctrP, &goA);
  } else {
    run_l1(bid - BPL, c0, Wih1, Whh1, h1ic, hist0, hist1, decW, decb,
           dec_out, hn, cn, flags0, flags1, zone, &ctrA, &ctrR, &ctrP, &goA, &goB);
  }
}

extern "C" void kernel_launch(void* const* d_in, const int* in_sizes, int n_in,
                              void* d_out, int out_size, void* d_ws, size_t ws_size,
                              hipStream_t stream){
  const int*   inputs = (const int*)d_in[0];
  const float* h0     = (const float*)d_in[1];
  const float* c0     = (const float*)d_in[2];
  const float* emb    = (const float*)d_in[3];
  const float* Wih0   = (const float*)d_in[4];
  const float* Whh0   = (const float*)d_in[5];
  const float* Wih1   = (const float*)d_in[6];
  const float* Whh1   = (const float*)d_in[7];
  const float* decW   = (const float*)d_in[8];
  const float* decb   = (const float*)d_in[9];

  char* ws = (char*)d_ws;
  size_t off = 0;
  auto alloc = [&](size_t bytes) -> void* {
    void* p = ws + off;
    off += (bytes + 255) & ~(size_t)255;
    return p;
  };
  us* emb_bf = (us*)alloc((size_t)VV * EE * 2);        // 51.2 MB
  us* hist0  = (us*)alloc((size_t)TT * BBHH * 2);      // 64 MB
  us* hist1  = (us*)alloc((size_t)TT * BBHH * 2);      // 64 MB
  us* h0ic   = (us*)alloc((size_t)BBHH * 2);
  us* h1ic   = (us*)alloc((size_t)BBHH * 2);
  unsigned* flags = (unsigned*)alloc((size_t)256 * 4);

  float* out = (float*)d_out;            // decoded [B]
  float* hn  = out + BB;                 // [2,B,H]
  float* cn  = out + BB + 2 * BBHH;      // [2,B,H]

  hipMemsetAsync(flags, 0, 256 * 4, stream);
  hipMemsetAsync(out, 0, BB * 4, stream);

  cast_f2b<<<2048, 256, 0, stream>>>(emb, emb_bf, (long)VV * EE);
  init_h<<<BBHH / 256, 256, 0, stream>>>(h0, h0ic, h1ic);

  lstm_persist<<<NBLK, 512, 0, stream>>>(inputs, c0, emb_bf,
                                         Wih0, Whh0, Wih1, Whh1,
                                         h0ic, h1ic, hist0, hist1,
                                         decW, decb, out, hn, cn, flags);
}